// Round 4
// baseline (1144.431 us; speedup 1.0000x reference)
//
#include <hip/hip_runtime.h>
#include <hip/hip_bf16.h>
#include <math.h>

typedef float f32x4 __attribute__((ext_vector_type(4)));
typedef short short8 __attribute__((ext_vector_type(8)));
typedef unsigned short u16x8 __attribute__((ext_vector_type(8)));

static __device__ __forceinline__ unsigned short f2bf(float f) {
    unsigned u = __builtin_bit_cast(unsigned, f);
    unsigned r = (u + 0x7FFFu + ((u >> 16) & 1u)) >> 16;
    return (unsigned short)r;
}
static __device__ __forceinline__ float bf2f(unsigned short h) {
    unsigned u = ((unsigned)h) << 16;
    return __builtin_bit_cast(float, u);
}
static __device__ __forceinline__ float fast_tanh(float x) {
    float ax = fminf(fmaxf(x, -9.f), 9.f);
    float e = __expf(2.f * ax);
    return 1.f - 2.f / (e + 1.f);
}

#define GLD16(g, l) __builtin_amdgcn_global_load_lds(                        \
    (const __attribute__((address_space(1))) void*)(g),                      \
    (__attribute__((address_space(3))) void*)(l), 16, 0, 0)

// ---------------------------------------------------------------------------
// PREP (fused): [0,16384): enc fp32->bf16; [16384,16640): Ws^T -> bf16;
// [16640,16896): base partials (8 e-chunks x 32 b)
// ---------------------------------------------------------------------------
__global__ __launch_bounds__(256) void prep_kernel(
    const float* __restrict__ enc, unsigned short* __restrict__ encB,
    const float* __restrict__ ws, unsigned short* __restrict__ wst,
    const float* __restrict__ dh, const float* __restrict__ whk,
    float* __restrict__ base_part)
{
    __shared__ unsigned short tile[64][65];
    __shared__ float dS[128];
    const int bid = blockIdx.x, tid = threadIdx.x;

    if (bid < 16384) {
        const size_t base0 = (size_t)bid * 4096;
#pragma unroll
        for (int i = 0; i < 4; i++) {
            size_t g = base0 + (size_t)i * 1024 + tid * 4;
            f32x4 v = *(const f32x4*)(enc + g);
            ushort4 w;
            w.x = f2bf(v.x); w.y = f2bf(v.y); w.z = f2bf(v.z); w.w = f2bf(v.w);
            *(ushort4*)(encB + g) = w;
        }
    } else if (bid < 16640) {
        const int b2 = bid - 16384;
        const int e0 = (b2 & 15) * 64, u0 = (b2 >> 4) * 64;
#pragma unroll
        for (int i = 0; i < 16; i++) {
            int idx = i * 256 + tid;
            int r = idx >> 6, c = idx & 63;
            tile[r][c] = f2bf(ws[(size_t)(e0 + r) * 1024 + u0 + c]);
        }
        __syncthreads();
#pragma unroll
        for (int i = 0; i < 16; i++) {
            int idx = i * 256 + tid;
            int r = idx >> 6, c = idx & 63;
            wst[(size_t)(u0 + r) * 1024 + e0 + c] = tile[c][r];
        }
    } else {
        const int b3 = bid - 16640;
        const int b = b3 & 31, ec = b3 >> 5;
        const int e0 = ec * 128;
        if (tid < 128) dS[tid] = dh[b * 1024 + e0 + tid];
        __syncthreads();
        f32x4 acc = {0.f, 0.f, 0.f, 0.f};
#pragma unroll 4
        for (int e = 0; e < 128; e++)
            acc += dS[e] * *(const f32x4*)(whk + (size_t)(e0 + e) * 1024 + tid * 4);
        *(f32x4*)(base_part + (size_t)ec * 32768 + b * 1024 + tid * 4) = acc;
    }
}

// ---------------------------------------------------------------------------
// K2: 256x256-tile GEMM, 4 phases / 2 K-tiles, ONE-PHASE-AHEAD register
// prefetch: each phase issues ds_reads for the NEXT phase's MFMAs (reads get
// a full phase + 2 barriers to land -> MFMA never stalls on fresh LDS reads).
// Fragment sets: aFA/aFB (row alternation), bfE/bfO (even/odd tile).
// LDS caps occupancy at 1 block/CU (8 waves), so the +128 VGPR is free.
// Stages: uniform 2 half-tiles/phase. vmcnt(4) at end-P0 (drains prev-P2+P3
// -> buf1 T(2i+1) landed before P1 reads it) and end-P2 (drains P0+P1 ->
// buf0 T(2i+2) landed before P3 reads it). All stage-vs-LDS-read WAR pairs
// barrier-separated (liveness table re-derived for the shifted read times).
// ---------------------------------------------------------------------------
#define BARRM() asm volatile("s_barrier" ::: "memory")
#define PRIO1() __builtin_amdgcn_s_setprio(1)
#define PRIO0() __builtin_amdgcn_s_setprio(0)
#define VMC8()  asm volatile("s_waitcnt vmcnt(8)" ::: "memory")
#define VMC4()  asm volatile("s_waitcnt vmcnt(4)" ::: "memory")
#define VMC0()  asm volatile("s_waitcnt vmcnt(0)" ::: "memory")

__global__ __launch_bounds__(512, 2) void score_gemm_8ph(
    const unsigned short* __restrict__ encB,
    const unsigned short* __restrict__ wst,
    const float* __restrict__ base_part,      // [8][32*1024]
    const float* __restrict__ cov,
    const float* __restrict__ wc,
    const float* __restrict__ vk,
    const float* __restrict__ wsb, const float* __restrict__ whb,
    const float* __restrict__ wcb,
    const int* __restrict__ ucov,
    float* __restrict__ score_part)           // [4][65536]
{
    __shared__ __align__(16) unsigned short As[2][16384];  // 2 x 32 KB
    __shared__ __align__(16) unsigned short Bs[2][16384];  // 2 x 32 KB

    const int tid = threadIdx.x;
    const int bid = blockIdx.x;
    // XCD swizzle: nwg=1024 (%8==0). Same-XCD walks u fastest -> A-panel L2 hit.
    const int sidx = bid >> 3;
    const int row_blk = (bid & 7) * 32 + (sidx >> 2);
    const int u_blk = sidx & 3;
    const int row0 = row_blk << 8;
    const int u0 = u_blk << 8;

    const int lane = tid & 63;
    const int wid  = tid >> 6;
    const int wm = wid >> 2, wn = wid & 3;       // 2 x 4 wave grid
    const int l16 = lane & 15, quad = lane >> 4;

    // ---- staging setup: half-tile = 16 KB, 16 units of 8 rows x 64 k.
    // LDS dest linear; global source chunk pre-swizzled: slot s at row r holds
    // logical chunk s ^ (r&7)  (involution; reader XORs the same).
    const int k8 = (lane & 7) ^ (lane >> 3);
    unsigned offA[2][2], offB[2][2];
    int dstA[2][2], dstB[2][2];
#pragma unroll
    for (int g = 0; g < 2; g++) {
        const int uu = wid * 2 + g;
#pragma unroll
        for (int h = 0; h < 2; h++) {
            const int ra = ((uu & 8) << 4) + (h << 6) + ((uu & 7) << 3);
            const int rb = ((uu >> 2) << 6) + (h << 5) + ((uu & 3) << 3);
            dstA[g][h] = ra * 64 + lane * 8;
            dstB[g][h] = rb * 64 + lane * 8;
            offA[g][h] = (unsigned)(row0 + ra + (lane >> 3)) * 1024u + (unsigned)(k8 * 8);
            offB[g][h] = (unsigned)(u0 + rb + (lane >> 3)) * 1024u + (unsigned)(k8 * 8);
        }
    }

    // ---- fragment-read setup (swizzled ds_read_b128)
    const int aBase = (wm * 128 + l16) * 64;
    const int bBase = (wn * 64 + l16) * 64;
    const int ch0 = ((quad) ^ (l16 & 7)) * 8;        // kslice 0
    const int ch1 = ((4 + quad) ^ (l16 & 7)) * 8;    // kslice 1

#define STAGE_A(bf, h, kt) do {                                             \
    GLD16(encB + offA[0][h] + ((kt) << 6), &As[bf][dstA[0][h]]);            \
    GLD16(encB + offA[1][h] + ((kt) << 6), &As[bf][dstA[1][h]]); } while (0)
#define STAGE_B(bf, h, kt) do {                                             \
    GLD16(wst + offB[0][h] + ((kt) << 6), &Bs[bf][dstB[0][h]]);             \
    GLD16(wst + offB[1][h] + ((kt) << 6), &Bs[bf][dstB[1][h]]); } while (0)

    f32x4 acc[8][4] = {};
    short8 aFA[4][2], aFB[4][2];          // A row-frag double buffer
    short8 bfE[2][2][2], bfO[2][2][2];    // B full-tile frags, even/odd tile

#define LOAD_A(bf, r, DST) do {                                             \
    _Pragma("unroll")                                                       \
    for (int fi = 0; fi < 4; fi++) {                                        \
        DST[fi][0] = *(const short8*)&As[bf][aBase + (r)*4096 + fi*1024 + ch0]; \
        DST[fi][1] = *(const short8*)&As[bf][aBase + (r)*4096 + fi*1024 + ch1]; \
    } } while (0)
#define LOAD_B(bf, DST) do {                                                \
    _Pragma("unroll")                                                       \
    for (int c = 0; c < 2; c++)                                             \
    _Pragma("unroll")                                                       \
    for (int fj = 0; fj < 2; fj++) {                                        \
        DST[c][fj][0] = *(const short8*)&Bs[bf][bBase + c*2048 + fj*1024 + ch0]; \
        DST[c][fj][1] = *(const short8*)&Bs[bf][bBase + c*2048 + fj*1024 + ch1]; \
    } } while (0)
#define MFMA_ROW(r, AF, BF) do {                                            \
    _Pragma("unroll")                                                       \
    for (int ks = 0; ks < 2; ks++)                                          \
    _Pragma("unroll")                                                       \
    for (int fi = 0; fi < 4; fi++)                                          \
    _Pragma("unroll")                                                       \
    for (int c = 0; c < 2; c++)                                             \
    _Pragma("unroll")                                                       \
    for (int fj = 0; fj < 2; fj++)                                          \
        acc[(r)*4+fi][c*2+fj] = __builtin_amdgcn_mfma_f32_16x16x32_bf16(    \
            AF[fi][ks], BF[c][fj][ks], acc[(r)*4+fi][c*2+fj], 0, 0, 0);     \
    } while (0)

    // ---- prologue: stage T0 + T1 (16 GLD); drain T0; pre-read P0's operands
    STAGE_A(0, 0, 0); STAGE_B(0, 0, 0); STAGE_B(0, 1, 0); STAGE_A(0, 1, 0);
    STAGE_A(1, 0, 1); STAGE_B(1, 0, 1); STAGE_B(1, 1, 1); STAGE_A(1, 1, 1);
    VMC8();                               // T0 landed; T1's 8 stay in flight
    BARRM();
    LOAD_A(0, 0, aFA); LOAD_B(0, bfE);    // operands for first P0

    // ---- main loop: i=0..6, tiles 2i (buf0) and 2i+1 (buf1)
#pragma unroll 1
    for (int i = 0; i < 7; i++) {
        const int t2 = 2 * i + 2, t3 = 2 * i + 3;
        // P0: MFMA buf0 row0 (regs from prev-P3); read buf0 row1;
        //     stage A_r0,B_c0 (buf0,t2). VMC4 drains prev-P2+P3 -> buf1 ready.
        LOAD_A(0, 1, aFB);
        STAGE_A(0, 0, t2); STAGE_B(0, 0, t2);
        PRIO1(); MFMA_ROW(0, aFA, bfE); PRIO0();
        VMC4();
        BARRM();
        // P1: MFMA buf0 row1; read buf1 row0 + B; stage B_c1,A_r1 (buf0,t2).
        LOAD_A(1, 0, aFA); LOAD_B(1, bfO);
        STAGE_B(0, 1, t2); STAGE_A(0, 1, t2);
        PRIO1(); MFMA_ROW(1, aFB, bfE); PRIO0();
        BARRM();
        // P2: MFMA buf1 row0; read buf1 row1; stage A_r0,B_c0 (buf1,t3).
        //     VMC4 drains P0+P1 -> buf0 (t2) ready for P3's reads.
        LOAD_A(1, 1, aFB);
        STAGE_A(1, 0, t3); STAGE_B(1, 0, t3);
        PRIO1(); MFMA_ROW(0, aFA, bfO); PRIO0();
        VMC4();
        BARRM();
        // P3: MFMA buf1 row1; read buf0 (t2) row0 + B; stage B_c1,A_r1 (buf1,t3).
        LOAD_A(0, 0, aFA); LOAD_B(0, bfE);
        STAGE_B(1, 1, t3); STAGE_A(1, 1, t3);
        PRIO1(); MFMA_ROW(1, aFB, bfO); PRIO0();
        BARRM();
    }

    // ---- peeled final iteration: tiles 14 (buf0), 15 (buf1); no stages
    // P0
    LOAD_A(0, 1, aFB);
    PRIO1(); MFMA_ROW(0, aFA, bfE); PRIO0();
    VMC0();                               // T15 fully landed
    BARRM();
    // P1
    LOAD_A(1, 0, aFA); LOAD_B(1, bfO);
    PRIO1(); MFMA_ROW(1, aFB, bfE); PRIO0();
    BARRM();
    // P2
    LOAD_A(1, 1, aFB);
    PRIO1(); MFMA_ROW(0, aFA, bfO); PRIO0();
    BARRM();
    // P3
    PRIO1(); MFMA_ROW(1, aFB, bfO); PRIO0();

    // ---- epilogue: tanh(acc + base + cov*wc) * v; reduce over 256 u-cols
    const int use_cov = *ucov;
    const int b = row0 >> 11;
    float baseR[4], wcR[4], vvR[4];
#pragma unroll
    for (int cf = 0; cf < 4; cf++) {
        int u = u0 + wn * 64 + cf * 16 + l16;
        float s = wsb[u] + whb[u] + (use_cov ? wcb[u] : 0.f);
#pragma unroll
        for (int p = 0; p < 8; p++) s += base_part[p * 32768 + b * 1024 + u];
        baseR[cf] = s;
        wcR[cf] = use_cov ? wc[u] : 0.f;
        vvR[cf] = vk[u];
    }
    float* sred = (float*)&Bs[0][0];
#pragma unroll
    for (int rf = 0; rf < 8; rf++) {
        float part[4] = {0.f, 0.f, 0.f, 0.f};
#pragma unroll
        for (int j = 0; j < 4; j++) {
            int rl = wm * 128 + rf * 16 + quad * 4 + j;
            float cvv = use_cov ? cov[row0 + rl] : 0.f;
#pragma unroll
            for (int cf = 0; cf < 4; cf++) {
                float pre = acc[rf][cf][j] + baseR[cf] + cvv * wcR[cf];
                part[j] += fast_tanh(pre) * vvR[cf];
            }
        }
#pragma unroll
        for (int j = 0; j < 4; j++) {
            float v = part[j];
            v += __shfl_xor(v, 1);
            v += __shfl_xor(v, 2);
            v += __shfl_xor(v, 4);
            v += __shfl_xor(v, 8);
            if (l16 == 0) sred[wn * 256 + wm * 128 + rf * 16 + quad * 4 + j] = v;
        }
    }
    __syncthreads();
    if (tid < 256)
        score_part[(size_t)u_blk * 65536 + row0 + tid] =
            sred[tid] + sred[256 + tid] + sred[512 + tid] + sred[768 + tid];

#undef STAGE_A
#undef STAGE_B
#undef LOAD_A
#undef LOAD_B
#undef MFMA_ROW
}

// ---------------------------------------------------------------------------
// K3 (fast path): softmax FUSED into context. grid (32 b, 16 ec) x 256.
// Each block recomputes row-softmax from score planes (deterministic,
// identical across ec); ec==0 writes attn/cov outputs.
// ---------------------------------------------------------------------------
__global__ __launch_bounds__(256) void context_fused(
    const unsigned short* __restrict__ encB,
    const float* __restrict__ score_part, int nplanes,
    const float* __restrict__ vb,
    const int* __restrict__ mask, const float* __restrict__ cov,
    const int* __restrict__ ucov,
    float* __restrict__ attn_out, float* __restrict__ cov_out,
    float* __restrict__ out_ctx)
{
    __shared__ float aS[2048];
    __shared__ float red[4][64];
    __shared__ float redM[4], redS[4];
    const int b = blockIdx.x, ec = blockIdx.y, tid = threadIdx.x;
    const int e0 = ec * 64;
    const int wv = tid >> 6;
    const float vbv = vb[0];
    const int uc = *ucov;

    // ---- softmax phase: 8 consecutive l per thread
    const int l0 = tid * 8;
    float sv[8] = {0.f, 0.f, 0.f, 0.f, 0.f, 0.f, 0.f, 0.f};
    for (int p = 0; p < nplanes; p++) {
        const float* sp = score_part + (size_t)p * 65536 + b * 2048 + l0;
        f32x4 v0 = *(const f32x4*)sp;
        f32x4 v1 = *(const f32x4*)(sp + 4);
        sv[0] += v0.x; sv[1] += v0.y; sv[2] += v0.z; sv[3] += v0.w;
        sv[4] += v1.x; sv[5] += v1.y; sv[6] += v1.z; sv[7] += v1.w;
    }
    int4 mk0 = *(const int4*)(mask + b * 2048 + l0);
    int4 mk1 = *(const int4*)(mask + b * 2048 + l0 + 4);
    sv[0] = (sv[0] + vbv) * (float)mk0.x;
    sv[1] = (sv[1] + vbv) * (float)mk0.y;
    sv[2] = (sv[2] + vbv) * (float)mk0.z;
    sv[3] = (sv[3] + vbv) * (float)mk0.w;
    sv[4] = (sv[4] + vbv) * (float)mk1.x;
    sv[5] = (sv[5] + vbv) * (float)mk1.y;
    sv[6] = (sv[6] + vbv) * (float)mk1.z;
    sv[7] = (sv[7] + vbv) * (float)mk1.w;

    float m = sv[0];
#pragma unroll
    for (int j = 1; j < 8; j++) m = fmaxf(m, sv[j]);
#pragma unroll
    for (int off = 1; off < 64; off <<= 1) m = fmaxf(m, __shfl_xor(m, off));
    if ((tid & 63) == 0) redM[wv] = m;
    __syncthreads();
    const float M = fmaxf(fmaxf(redM[0], redM[1]), fmaxf(redM[2], redM[3]));

    float e[8], s = 0.f;
#pragma unroll
    for (int j = 0; j < 8; j++) { e[j] = __expf(sv[j] - M); s += e[j]; }
#pragma unroll
    for (int off = 1; off < 64; off <<= 1) s += __shfl_xor(s, off);
    if ((tid & 63) == 0) redS[wv] = s;
    __syncthreads();
    const float inv = 1.f / (redS[0] + redS[1] + redS[2] + redS[3]);

#pragma unroll
    for (int j = 0; j < 8; j++) {
        float a = e[j] * inv;
        aS[l0 + j] = a;
        if (ec == 0) {
            attn_out[b * 2048 + l0 + j] = a;
            cov_out[b * 2048 + l0 + j] = a + (uc ? cov[b * 2048 + l0 + j] : 0.f);
        }
    }
    __syncthreads();

    // ---- context phase
    const int es = (tid & 7) * 8;
    const int lo = tid >> 3;
    float acc[8] = {};
    for (int l = lo; l < 2048; l += 32) {
        u16x8 w = *(const u16x8*)(encB + (size_t)(b * 2048 + l) * 1024 + e0 + es);
        float a = aS[l];
#pragma unroll
        for (int j = 0; j < 8; j++) acc[j] = fmaf(a, bf2f(w[j]), acc[j]);
    }
#pragma unroll
    for (int j = 0; j < 8; j++) {
        float v = acc[j];
        v += __shfl_xor(v, 8);
        v += __shfl_xor(v, 16);
        v += __shfl_xor(v, 32);
        acc[j] = v;
    }
    if ((tid & 63) < 8) {
#pragma unroll
        for (int j = 0; j < 8; j++) red[wv][(tid & 7) * 8 + j] = acc[j];
    }
    __syncthreads();
    if (tid < 64)
        out_ctx[b * 1024 + e0 + tid] = red[0][tid] + red[1][tid] + red[2][tid] + red[3][tid];
}

// ---------------------------------------------------------------------------
// K3 (fallback): standalone softmax. grid 32 x 1024
// ---------------------------------------------------------------------------
__global__ __launch_bounds__(1024) void softmax_kernel(
    const float* __restrict__ score_part, int nplanes,
    const float* __restrict__ vb,
    const int* __restrict__ mask, const float* __restrict__ cov,
    const int* __restrict__ ucov,
    float* __restrict__ attn_out, float* __restrict__ cov_out)
{
    __shared__ float redA[16], redB[16];
    __shared__ float bc0, bc1;
    const int b = blockIdx.x, tid = threadIdx.x;
    const int i0 = b * 2048 + tid, i1 = i0 + 1024;
    const float vbv = vb[0];
    const int uc = *ucov;

    float s0 = 0.f, s1 = 0.f;
    for (int p = 0; p < nplanes; p++) {
        s0 += score_part[(size_t)p * 65536 + i0];
        s1 += score_part[(size_t)p * 65536 + i1];
    }
    s0 = (s0 + vbv) * (float)mask[i0];
    s1 = (s1 + vbv) * (float)mask[i1];

    float m = fmaxf(s0, s1);
#pragma unroll
    for (int off = 1; off < 64; off <<= 1) m = fmaxf(m, __shfl_xor(m, off));
    if ((tid & 63) == 0) redA[tid >> 6] = m;
    __syncthreads();
    if (tid < 16) {
        float v = redA[tid];
#pragma unroll
        for (int off = 1; off < 16; off <<= 1) v = fmaxf(v, __shfl_xor(v, off));
        if (tid == 0) bc0 = v;
    }
    __syncthreads();
    const float M = bc0;

    float e0 = __expf(s0 - M), e1 = __expf(s1 - M);
    float s = e0 + e1;
#pragma unroll
    for (int off = 1; off < 64; off <<= 1) s += __shfl_xor(s, off);
    if ((tid & 63) == 0) redB[tid >> 6] = s;
    __syncthreads();
    if (tid < 16) {
        float v = redB[tid];
#pragma unroll
        for (int off = 1; off < 16; off <<= 1) v += __shfl_xor(v, off);
        if (tid == 0) bc1 = v;
    }
    __syncthreads();
    const float inv = 1.f / bc1;

    float a0 = e0 * inv, a1 = e1 * inv;
    attn_out[i0] = a0;
    attn_out[i1] = a1;
    cov_out[i0] = a0 + (uc ? cov[i0] : 0.f);
    cov_out[i1] = a1 + (uc ? cov[i1] : 0.f);
}

// ---------------------------------------------------------------------------
// Fallback path (ws too small for bf16 enc): fp32-staging gemm + atomics.
// ---------------------------------------------------------------------------
#define BM 128
#define BN 128
#define BK 32
#define LDT 40
__global__ __launch_bounds__(256) void score_gemm_f32(
    const float* __restrict__ enc, const unsigned short* __restrict__ wst,
    const float* __restrict__ base_part, const float* __restrict__ cov,
    const float* __restrict__ wc, const float* __restrict__ vk,
    const float* __restrict__ wsb, const float* __restrict__ whb,
    const float* __restrict__ wcb,
    const int* __restrict__ ucov, float* __restrict__ score)
{
    __shared__ unsigned short As[BM * LDT];
    __shared__ unsigned short Bs[BN * LDT];
    __shared__ float covS[BM];
    __shared__ float baseS[BN], wcS[BN], vvS[BN];
    const int tid = threadIdx.x;
    const int row0 = blockIdx.x * BM, u0 = blockIdx.y * BN;
    const int b = row0 >> 11;
    const int use_cov = *ucov;
    if (tid < BM) covS[tid] = use_cov ? cov[row0 + tid] : 0.f;
    if (tid < BN) {
        int u = u0 + tid;
        float s = wsb[u] + whb[u] + (use_cov ? wcb[u] : 0.f);
#pragma unroll
        for (int p = 0; p < 8; p++) s += base_part[p * 32768 + b * 1024 + u];
        baseS[tid] = s;
        wcS[tid] = use_cov ? wc[u] : 0.f;
        vvS[tid] = vk[u];
    }
    const int lane = tid & 63, wid = tid >> 6;
    const int wm = wid >> 1, wn = wid & 1;
    const int l16 = lane & 15, quad = lane >> 4;
    f32x4 acc[4][4] = {};
    for (int k0 = 0; k0 < 1024; k0 += BK) {
        __syncthreads();
#pragma unroll
        for (int i = 0; i < 4; i++) {
            int f = i * 256 + tid;
            int r = f >> 3, c4 = f & 7;
            const float* p = enc + (size_t)(row0 + r) * 1024 + k0 + c4 * 4;
            ushort4 w;
            w.x = f2bf(p[0]); w.y = f2bf(p[1]); w.z = f2bf(p[2]); w.w = f2bf(p[3]);
            *(ushort4*)&As[r * LDT + c4 * 4] = w;
        }
#pragma unroll
        for (int i = 0; i < 2; i++) {
            int f = i * 256 + tid;
            int r = f >> 2, c8 = f & 3;
            uint4 w = *(const uint4*)(wst + (size_t)(u0 + r) * 1024 + k0 + c8 * 8);
            *(uint4*)&Bs[r * LDT + c8 * 8] = w;
        }
        __syncthreads();
        short8 a[4], bb[4];
#pragma unroll
        for (int t = 0; t < 4; t++) {
            a[t]  = *(const short8*)&As[(wm * 64 + t * 16 + l16) * LDT + quad * 8];
            bb[t] = *(const short8*)&Bs[(wn * 64 + t * 16 + l16) * LDT + quad * 8];
        }
#pragma unroll
        for (int i = 0; i < 4; i++)
#pragma unroll
            for (int j = 0; j < 4; j++)
                acc[i][j] = __builtin_amdgcn_mfma_f32_16x16x32_bf16(a[i], bb[j], acc[i][j], 0, 0, 0);
    }
#pragma unroll
    for (int i = 0; i < 4; i++) {
        float part[4] = {0.f, 0.f, 0.f, 0.f};
#pragma unroll
        for (int r = 0; r < 4; r++) {
            float cv = covS[wm * 64 + i * 16 + quad * 4 + r];
#pragma unroll
            for (int j = 0; j < 4; j++) {
                int ul = wn * 64 + j * 16 + l16;
                part[r] += fast_tanh(acc[i][j][r] + baseS[ul] + cv * wcS[ul]) * vvS[ul];
            }
        }
#pragma unroll
        for (int r = 0; r < 4; r++) {
            float v = part[r];
            v += __shfl_xor(v, 1);
            v += __shfl_xor(v, 2);
            v += __shfl_xor(v, 4);
            v += __shfl_xor(v, 8);
            if (l16 == 0)
                atomicAdd(&score[row0 + wm * 64 + i * 16 + quad * 4 + r], v);
        }
    }
}

__global__ __launch_bounds__(256) void context_f32(const float* __restrict__ enc,
                                                   const float* __restrict__ attn,
                                                   float* __restrict__ ctx) {
    __shared__ float aS[128];
    const int b = blockIdx.x, lc = blockIdx.y, tid = threadIdx.x;
    const int l0 = lc * 128;
    if (tid < 128) aS[tid] = attn[b * 2048 + l0 + tid];
    __syncthreads();
    const float* p = enc + ((size_t)(b * 2048 + l0)) * 1024 + tid * 4;
    f32x4 acc = {0.f, 0.f, 0.f, 0.f};
#pragma unroll 4
    for (int l = 0; l < 128; l++) acc += *(const f32x4*)(p + (size_t)l * 1024) * aS[l];
    float* o = ctx + b * 1024 + tid * 4;
    atomicAdd(o + 0, acc.x);
    atomicAdd(o + 1, acc.y);
    atomicAdd(o + 2, acc.z);
    atomicAdd(o + 3, acc.w);
}

__global__ __launch_bounds__(256) void prep2_kernel(
    const float* __restrict__ ws, unsigned short* __restrict__ wst,
    const float* __restrict__ dh, const float* __restrict__ whk,
    float* __restrict__ base_part)
{
    __shared__ unsigned short tile[64][65];
    __shared__ float dS[128];
    const int bid = blockIdx.x, tid = threadIdx.x;
    if (bid < 256) {
        const int e0 = (bid & 15) * 64, u0 = (bid >> 4) * 64;
#pragma unroll
        for (int i = 0; i < 16; i++) {
            int idx = i * 256 + tid;
            int r = idx >> 6, c = idx & 63;
            tile[r][c] = f2bf(ws[(size_t)(e0 + r) * 1024 + u0 + c]);
        }
        __syncthreads();
#pragma unroll
        for (int i = 0; i < 16; i++) {
            int idx = i * 256 + tid;
            int r = idx >> 6, c = idx & 63;
            wst[(size_t)(u0 + r) * 1024 + e0 + c] = tile[c][r];
        }
    } else {
        const int b3 = bid - 256;
        const int b = b3 & 31, ec = b3 >> 5;
        const int e0 = ec * 128;
        if (tid < 128) dS[tid] = dh[b * 1024 + e0 + tid];
        __syncthreads();
        f32x4 acc = {0.f, 0.f, 0.f, 0.f};
#pragma unroll 4
        for (int e = 0; e < 128; e++)
            acc += dS[e] * *(const f32x4*)(whk + (size_t)(e0 + e) * 1024 + tid * 4);
        *(f32x4*)(base_part + (size_t)ec * 32768 + b * 1024 + tid * 4) = acc;
    }
}

// ---------------------------------------------------------------------------
extern "C" void kernel_launch(void* const* d_in, const int* in_sizes, int n_in,
                              void* d_out, int out_size, void* d_ws, size_t ws_size,
                              hipStream_t stream) {
    const float* dec_hidden = (const float*)d_in[0];
    const float* enc        = (const float*)d_in[1];
    const float* prev_cov   = (const float*)d_in[2];
    const float* Ws_k       = (const float*)d_in[3];
    const float* Ws_b       = (const float*)d_in[4];
    const float* Wh_k       = (const float*)d_in[5];
    const float* Wh_b       = (const float*)d_in[6];
    const float* Wc_k       = (const float*)d_in[7];
    const float* Wc_b       = (const float*)d_in[8];
    const float* V_k        = (const float*)d_in[9];
    const float* V_b        = (const float*)d_in[10];
    const int*   mask       = (const int*)d_in[11];
    const int*   ucov       = (const int*)d_in[12];

    float* out_ctx  = (float*)d_out;
    float* out_attn = out_ctx + 32 * 1024;
    float* out_cov  = out_attn + 65536;

    char* ws = (char*)d_ws;
    unsigned short* wst = (unsigned short*)ws;                    // 2 MB
    float* base_part  = (float*)(ws + 2097152);                   // 1 MB  [8][32768]
    float* score_part = (float*)(ws + 3145728);                   // 2 MB  (4 planes used)
    unsigned short* encB = (unsigned short*)(ws + 5242880);       // 128 MB
    const size_t need_fast = 5242880 + (size_t)32 * 2048 * 1024 * 2;

    if (ws_size >= need_fast) {
        prep_kernel<<<16896, 256, 0, stream>>>(enc, encB, Ws_k, wst, dec_hidden, Wh_k, base_part);
        score_gemm_8ph<<<dim3(1024), dim3(512), 0, stream>>>(
            encB, wst, base_part, prev_cov, Wc_k, V_k, Ws_b, Wh_b, Wc_b, ucov, score_part);
        context_fused<<<dim3(32, 16), 256, 0, stream>>>(
            encB, score_part, 4, V_b, mask, prev_cov, ucov, out_attn, out_cov, out_ctx);
    } else {
        hipMemsetAsync(score_part, 0, 65536 * sizeof(float), stream);
        hipMemsetAsync(out_ctx, 0, 32 * 1024 * sizeof(float), stream);
        prep2_kernel<<<512, 256, 0, stream>>>(Ws_k, wst, dec_hidden, Wh_k, base_part);
        score_gemm_f32<<<dim3(512, 8), 256, 0, stream>>>(
            enc, wst, base_part, prev_cov, Wc_k, V_k, Ws_b, Wh_b, Wc_b, ucov, score_part);
        softmax_kernel<<<32, 1024, 0, stream>>>(score_part, 1, V_b, mask, prev_cov, ucov, out_attn, out_cov);
        context_f32<<<dim3(32, 16), 256, 0, stream>>>(enc, out_attn, out_ctx);
    }
}

// Round 6
// 569.263 us; speedup vs baseline: 2.0104x; 2.0104x over previous
//
#include <hip/hip_runtime.h>
#include <hip/hip_bf16.h>
#include <math.h>

typedef float f32x4 __attribute__((ext_vector_type(4)));
typedef short short8 __attribute__((ext_vector_type(8)));
typedef unsigned short u16x8 __attribute__((ext_vector_type(8)));

static __device__ __forceinline__ unsigned short f2bf(float f) {
    unsigned u = __builtin_bit_cast(unsigned, f);
    unsigned r = (u + 0x7FFFu + ((u >> 16) & 1u)) >> 16;
    return (unsigned short)r;
}
static __device__ __forceinline__ float bf2f(unsigned short h) {
    unsigned u = ((unsigned)h) << 16;
    return __builtin_bit_cast(float, u);
}
static __device__ __forceinline__ float fast_tanh(float x) {
    float ax = fminf(fmaxf(x, -9.f), 9.f);
    float e = __expf(2.f * ax);
    return 1.f - 2.f / (e + 1.f);
}

#define GLD16(g, l) __builtin_amdgcn_global_load_lds(                        \
    (const __attribute__((address_space(1))) void*)(g),                      \
    (__attribute__((address_space(3))) void*)(l), 16, 0, 0)

// ---------------------------------------------------------------------------
// PREP (fused): [0,16384): enc fp32->bf16 (NT loads: don't evict encB from
// L3); [16384,16640): Ws^T -> bf16; [16640,16896): base partials
// ---------------------------------------------------------------------------
__global__ __launch_bounds__(256) void prep_kernel(
    const float* __restrict__ enc, unsigned short* __restrict__ encB,
    const float* __restrict__ ws, unsigned short* __restrict__ wst,
    const float* __restrict__ dh, const float* __restrict__ whk,
    float* __restrict__ base_part)
{
    __shared__ unsigned short tile[64][65];
    __shared__ float dS[128];
    const int bid = blockIdx.x, tid = threadIdx.x;

    if (bid < 16384) {
        const size_t base0 = (size_t)bid * 4096;
#pragma unroll
        for (int i = 0; i < 2; i++) {
            size_t g = base0 + (size_t)i * 2048 + tid * 8;
            f32x4 v0 = __builtin_nontemporal_load((const f32x4*)(enc + g));
            f32x4 v1 = __builtin_nontemporal_load((const f32x4*)(enc + g) + 1);
            u16x8 w;
            w[0] = f2bf(v0.x); w[1] = f2bf(v0.y); w[2] = f2bf(v0.z); w[3] = f2bf(v0.w);
            w[4] = f2bf(v1.x); w[5] = f2bf(v1.y); w[6] = f2bf(v1.z); w[7] = f2bf(v1.w);
            *(u16x8*)(encB + g) = w;
        }
    } else if (bid < 16640) {
        const int b2 = bid - 16384;
        const int e0 = (b2 & 15) * 64, u0 = (b2 >> 4) * 64;
#pragma unroll
        for (int i = 0; i < 16; i++) {
            int idx = i * 256 + tid;
            int r = idx >> 6, c = idx & 63;
            tile[r][c] = f2bf(ws[(size_t)(e0 + r) * 1024 + u0 + c]);
        }
        __syncthreads();
#pragma unroll
        for (int i = 0; i < 16; i++) {
            int idx = i * 256 + tid;
            int r = idx >> 6, c = idx & 63;
            wst[(size_t)(u0 + r) * 1024 + e0 + c] = tile[c][r];
        }
    } else {
        const int b3 = bid - 16640;
        const int b = b3 & 31, ec = b3 >> 5;
        const int e0 = ec * 128;
        if (tid < 128) dS[tid] = dh[b * 1024 + e0 + tid];
        __syncthreads();
        f32x4 acc = {0.f, 0.f, 0.f, 0.f};
#pragma unroll 4
        for (int e = 0; e < 128; e++)
            acc += dS[e] * *(const f32x4*)(whk + (size_t)(e0 + e) * 1024 + tid * 4);
        *(f32x4*)(base_part + (size_t)ec * 32768 + b * 1024 + tid * 4) = acc;
    }
}

// ---------------------------------------------------------------------------
// K2: 256x256-tile GEMM, 4 large phases per 2-K-tile iteration (R3 schedule,
// known-good 178 us). Each phase: {ds_reads ; MFMA x32 ; 1-3 stages} in one
// unfenced region; asm s_barrier at phase ends; counted vmcnt before the
// barrier that precedes new-buffer reads. NOTE: non-acc VGPR budget is FULL
// at this geometry (R4: +64 frag VGPRs -> spill, 4x slowdown). Do not add
// register prefetch here.
// ---------------------------------------------------------------------------
#define BARRM() asm volatile("s_barrier" ::: "memory")
#define PRIO1() __builtin_amdgcn_s_setprio(1)
#define PRIO0() __builtin_amdgcn_s_setprio(0)
#define VMC6()  asm volatile("s_waitcnt vmcnt(6)" ::: "memory")
#define VMC4()  asm volatile("s_waitcnt vmcnt(4)" ::: "memory")
#define VMC0()  asm volatile("s_waitcnt vmcnt(0)" ::: "memory")

__global__ __launch_bounds__(512, 2) void score_gemm_8ph(
    const unsigned short* __restrict__ encB,
    const unsigned short* __restrict__ wst,
    const float* __restrict__ base_part,      // [8][32*1024]
    const float* __restrict__ cov,
    const float* __restrict__ wc,
    const float* __restrict__ vk,
    const float* __restrict__ wsb, const float* __restrict__ whb,
    const float* __restrict__ wcb,
    const int* __restrict__ ucov,
    float* __restrict__ score_part)           // [4][65536]
{
    __shared__ __align__(16) unsigned short As[2][16384];  // 2 x 32 KB
    __shared__ __align__(16) unsigned short Bs[2][16384];  // 2 x 32 KB

    const int tid = threadIdx.x;
    const int bid = blockIdx.x;
    // XCD swizzle: nwg=1024 (%8==0). Same-XCD walks u fastest -> A-panel L2 hit.
    const int sidx = bid >> 3;
    const int row_blk = (bid & 7) * 32 + (sidx >> 2);
    const int u_blk = sidx & 3;
    const int row0 = row_blk << 8;
    const int u0 = u_blk << 8;

    const int lane = tid & 63;
    const int wid  = tid >> 6;
    const int wm = wid >> 2, wn = wid & 3;       // 2 x 4 wave grid
    const int l16 = lane & 15, quad = lane >> 4;

    // ---- staging setup: half-tile = 16 KB, 16 units of 8 rows x 64 k.
    // LDS dest linear; global source chunk pre-swizzled: slot s at row r holds
    // logical chunk s ^ (r&7)  (involution; reader XORs the same).
    const int k8 = (lane & 7) ^ (lane >> 3);
    unsigned offA[2][2], offB[2][2];
    int dstA[2][2], dstB[2][2];
#pragma unroll
    for (int g = 0; g < 2; g++) {
        const int uu = wid * 2 + g;
#pragma unroll
        for (int h = 0; h < 2; h++) {
            const int ra = ((uu & 8) << 4) + (h << 6) + ((uu & 7) << 3);
            const int rb = ((uu >> 2) << 6) + (h << 5) + ((uu & 3) << 3);
            dstA[g][h] = ra * 64 + lane * 8;
            dstB[g][h] = rb * 64 + lane * 8;
            offA[g][h] = (unsigned)(row0 + ra + (lane >> 3)) * 1024u + (unsigned)(k8 * 8);
            offB[g][h] = (unsigned)(u0 + rb + (lane >> 3)) * 1024u + (unsigned)(k8 * 8);
        }
    }

    // ---- fragment-read setup (swizzled ds_read_b128)
    const int aBase = (wm * 128 + l16) * 64;
    const int bBase = (wn * 64 + l16) * 64;
    const int ch0 = ((quad) ^ (l16 & 7)) * 8;        // kslice 0
    const int ch1 = ((4 + quad) ^ (l16 & 7)) * 8;    // kslice 1

#define STAGE_A(bf, h, kt) do {                                             \
    GLD16(encB + offA[0][h] + ((kt) << 6), &As[bf][dstA[0][h]]);            \
    GLD16(encB + offA[1][h] + ((kt) << 6), &As[bf][dstA[1][h]]); } while (0)
#define STAGE_B(bf, h, kt) do {                                             \
    GLD16(wst + offB[0][h] + ((kt) << 6), &Bs[bf][dstB[0][h]]);             \
    GLD16(wst + offB[1][h] + ((kt) << 6), &Bs[bf][dstB[1][h]]); } while (0)

    f32x4 acc[8][4] = {};
    short8 aF[4][2], bF0[2][2], bF1[2][2];

#define LOAD_AF(bf, r) do {                                                 \
    _Pragma("unroll")                                                       \
    for (int fi = 0; fi < 4; fi++) {                                        \
        aF[fi][0] = *(const short8*)&As[bf][aBase + (r)*4096 + fi*1024 + ch0]; \
        aF[fi][1] = *(const short8*)&As[bf][aBase + (r)*4096 + fi*1024 + ch1]; \
    } } while (0)
#define LOAD_BF(bf, c, BF) do {                                             \
    _Pragma("unroll")                                                       \
    for (int fj = 0; fj < 2; fj++) {                                        \
        BF[fj][0] = *(const short8*)&Bs[bf][bBase + (c)*2048 + fj*1024 + ch0]; \
        BF[fj][1] = *(const short8*)&Bs[bf][bBase + (c)*2048 + fj*1024 + ch1]; \
    } } while (0)
#define MFMA16(r, c, BF) do {                                               \
    _Pragma("unroll")                                                       \
    for (int ks = 0; ks < 2; ks++)                                          \
    _Pragma("unroll")                                                       \
    for (int fi = 0; fi < 4; fi++)                                          \
    _Pragma("unroll")                                                       \
    for (int fj = 0; fj < 2; fj++)                                          \
        acc[(r)*4+fi][(c)*2+fj] = __builtin_amdgcn_mfma_f32_16x16x32_bf16(  \
            aF[fi][ks], BF[fj][ks], acc[(r)*4+fi][(c)*2+fj], 0, 0, 0);      \
    } while (0)

    // ---- prologue: 7 half-tiles (tile0 complete + A_r0/B_c0/B_c1 of tile1)
    STAGE_A(0, 0, 0);
    STAGE_B(0, 0, 0);
    STAGE_B(0, 1, 0);
    STAGE_A(0, 1, 0);
    STAGE_A(1, 0, 1);
    STAGE_B(1, 0, 1);
    STAGE_B(1, 1, 1);
    // 14 GLDs outstanding; drain the 8 of tile0 (leave tile1's 6 in flight),
    // THEN barrier, THEN reads (cross-wave safe ordering).
    VMC6();
    BARRM();

    // ---- main loop: i=0..6, tiles 2i (buf0) and 2i+1 (buf1)
#pragma unroll 1
    for (int i = 0; i < 7; i++) {
        const int t1 = 2 * i + 1, t2 = 2 * i + 2, t3 = 2 * i + 3;
        // P0: buf0 quadrants (0,0),(0,1). Stage A_r1(t1)->buf1 (region's last
        // read was prev-P3, drained before prev-P3's MFMAs + barrier).
        LOAD_AF(0, 0); LOAD_BF(0, 0, bF0); LOAD_BF(0, 1, bF1);
        STAGE_A(1, 1, t1);
        PRIO1(); MFMA16(0, 0, bF0); MFMA16(0, 1, bF1); PRIO0();
        BARRM();
        // P1: buf0 quadrants (1,0),(1,1). Stage A_r0,B_c0(t2)->buf0 (read at P0).
        // VMC4 before barrier: drains through A_r1(t1) -> buf1 complete for P2.
        LOAD_AF(0, 1);
        STAGE_A(0, 0, t2); STAGE_B(0, 0, t2);
        PRIO1(); MFMA16(1, 0, bF0); MFMA16(1, 1, bF1); PRIO0();
        VMC4();
        BARRM();
        // P2: buf1 quadrants (0,0),(0,1). Stage B_c1,A_r1(t2)->buf0 (read P0/P1).
        LOAD_AF(1, 0); LOAD_BF(1, 0, bF0); LOAD_BF(1, 1, bF1);
        STAGE_B(0, 1, t2); STAGE_A(0, 1, t2);
        PRIO1(); MFMA16(0, 0, bF0); MFMA16(0, 1, bF1); PRIO0();
        BARRM();
        // P3: buf1 quadrants (1,0),(1,1). Stage A_r0,B_c0,B_c1(t3)->buf1 (read P2).
        // VMC6 before barrier: drains through A_r1(t2) -> buf0 complete for next P0.
        LOAD_AF(1, 1);
        STAGE_A(1, 0, t3); STAGE_B(1, 0, t3); STAGE_B(1, 1, t3);
        PRIO1(); MFMA16(1, 0, bF0); MFMA16(1, 1, bF1); PRIO0();
        VMC6();
        BARRM();
    }

    // ---- peeled final iteration: tiles 14 (buf0), 15 (buf1)
    // P0
    LOAD_AF(0, 0); LOAD_BF(0, 0, bF0); LOAD_BF(0, 1, bF1);
    STAGE_A(1, 1, 15);
    PRIO1(); MFMA16(0, 0, bF0); MFMA16(0, 1, bF1); PRIO0();
    BARRM();
    // P1 (no stages; full drain so buf1 tile15 is complete for P2)
    LOAD_AF(0, 1);
    PRIO1(); MFMA16(1, 0, bF0); MFMA16(1, 1, bF1); PRIO0();
    VMC0();
    BARRM();
    // P2
    LOAD_AF(1, 0); LOAD_BF(1, 0, bF0); LOAD_BF(1, 1, bF1);
    PRIO1(); MFMA16(0, 0, bF0); MFMA16(0, 1, bF1); PRIO0();
    BARRM();
    // P3
    LOAD_AF(1, 1);
    PRIO1(); MFMA16(1, 0, bF0); MFMA16(1, 1, bF1); PRIO0();

    // ---- epilogue: tanh(acc + base + cov*wc) * v; reduce over 256 u-cols
    const int use_cov = *ucov;
    const int b = row0 >> 11;
    float baseR[4], wcR[4], vvR[4];
#pragma unroll
    for (int cf = 0; cf < 4; cf++) {
        int u = u0 + wn * 64 + cf * 16 + l16;
        float s = wsb[u] + whb[u] + (use_cov ? wcb[u] : 0.f);
#pragma unroll
        for (int p = 0; p < 8; p++) s += base_part[p * 32768 + b * 1024 + u];
        baseR[cf] = s;
        wcR[cf] = use_cov ? wc[u] : 0.f;
        vvR[cf] = vk[u];
    }
    float* sred = (float*)&Bs[0][0];   // Bs[0] ds_reads all drained by peel-P0
#pragma unroll
    for (int rf = 0; rf < 8; rf++) {
        float part[4] = {0.f, 0.f, 0.f, 0.f};
#pragma unroll
        for (int j = 0; j < 4; j++) {
            int rl = wm * 128 + rf * 16 + quad * 4 + j;
            float cvv = use_cov ? cov[row0 + rl] : 0.f;
#pragma unroll
            for (int cf = 0; cf < 4; cf++) {
                float pre = acc[rf][cf][j] + baseR[cf] + cvv * wcR[cf];
                part[j] += fast_tanh(pre) * vvR[cf];
            }
        }
#pragma unroll
        for (int j = 0; j < 4; j++) {
            float v = part[j];
            v += __shfl_xor(v, 1);
            v += __shfl_xor(v, 2);
            v += __shfl_xor(v, 4);
            v += __shfl_xor(v, 8);
            if (l16 == 0) sred[wn * 256 + wm * 128 + rf * 16 + quad * 4 + j] = v;
        }
    }
    __syncthreads();
    if (tid < 256)
        score_part[(size_t)u_blk * 65536 + row0 + tid] =
            sred[tid] + sred[256 + tid] + sred[512 + tid] + sred[768 + tid];

#undef STAGE_A
#undef STAGE_B
#undef LOAD_AF
#undef LOAD_BF
#undef MFMA16
}

// ---------------------------------------------------------------------------
// K3 (fast path): softmax FUSED into context, 512 threads (16 waves/CU) for
// latency hiding. grid (32 b, 16 ec). Each block recomputes row-softmax
// (deterministic, identical across ec); ec==0 writes attn/cov outputs.
// ---------------------------------------------------------------------------
__global__ __launch_bounds__(512) void context_fused(
    const unsigned short* __restrict__ encB,
    const float* __restrict__ score_part, int nplanes,
    const float* __restrict__ vb,
    const int* __restrict__ mask, const float* __restrict__ cov,
    const int* __restrict__ ucov,
    float* __restrict__ attn_out, float* __restrict__ cov_out,
    float* __restrict__ out_ctx)
{
    __shared__ float aS[2048];
    __shared__ float red[8][64];
    __shared__ float redM[8], redS[8];
    const int b = blockIdx.x, ec = blockIdx.y, tid = threadIdx.x;
    const int e0 = ec * 64;
    const int wv = tid >> 6;
    const float vbv = vb[0];
    const int uc = *ucov;

    // ---- softmax phase: 4 consecutive l per thread
    const int l0 = tid * 4;
    float sv[4] = {0.f, 0.f, 0.f, 0.f};
    for (int p = 0; p < nplanes; p++) {
        f32x4 v0 = *(const f32x4*)(score_part + (size_t)p * 65536 + b * 2048 + l0);
        sv[0] += v0.x; sv[1] += v0.y; sv[2] += v0.z; sv[3] += v0.w;
    }
    int4 mk = *(const int4*)(mask + b * 2048 + l0);
    sv[0] = (sv[0] + vbv) * (float)mk.x;
    sv[1] = (sv[1] + vbv) * (float)mk.y;
    sv[2] = (sv[2] + vbv) * (float)mk.z;
    sv[3] = (sv[3] + vbv) * (float)mk.w;

    float m = fmaxf(fmaxf(sv[0], sv[1]), fmaxf(sv[2], sv[3]));
#pragma unroll
    for (int off = 1; off < 64; off <<= 1) m = fmaxf(m, __shfl_xor(m, off));
    if ((tid & 63) == 0) redM[wv] = m;
    __syncthreads();
    float M = redM[0];
#pragma unroll
    for (int w = 1; w < 8; w++) M = fmaxf(M, redM[w]);

    float e[4], s = 0.f;
#pragma unroll
    for (int j = 0; j < 4; j++) { e[j] = __expf(sv[j] - M); s += e[j]; }
#pragma unroll
    for (int off = 1; off < 64; off <<= 1) s += __shfl_xor(s, off);
    if ((tid & 63) == 0) redS[wv] = s;
    __syncthreads();
    float den = redS[0];
#pragma unroll
    for (int w = 1; w < 8; w++) den += redS[w];
    const float inv = 1.f / den;

#pragma unroll
    for (int j = 0; j < 4; j++) {
        float a = e[j] * inv;
        aS[l0 + j] = a;
        if (ec == 0) {
            attn_out[b * 2048 + l0 + j] = a;
            cov_out[b * 2048 + l0 + j] = a + (uc ? cov[b * 2048 + l0 + j] : 0.f);
        }
    }
    __syncthreads();

    // ---- context phase: lo = tid>>3 in [0,64), stride 64, 32 iterations
    const int es = (tid & 7) * 8;
    const int lo = tid >> 3;
    float acc[8] = {};
    for (int l = lo; l < 2048; l += 64) {
        u16x8 w = *(const u16x8*)(encB + (size_t)(b * 2048 + l) * 1024 + e0 + es);
        float a = aS[l];
#pragma unroll
        for (int j = 0; j < 8; j++) acc[j] = fmaf(a, bf2f(w[j]), acc[j]);
    }
#pragma unroll
    for (int j = 0; j < 8; j++) {
        float v = acc[j];
        v += __shfl_xor(v, 8);
        v += __shfl_xor(v, 16);
        v += __shfl_xor(v, 32);
        acc[j] = v;
    }
    if ((tid & 63) < 8) {
#pragma unroll
        for (int j = 0; j < 8; j++) red[wv][(tid & 7) * 8 + j] = acc[j];
    }
    __syncthreads();
    if (tid < 64) {
        float v = 0.f;
#pragma unroll
        for (int w = 0; w < 8; w++) v += red[w][tid];
        out_ctx[b * 1024 + e0 + tid] = v;
    }
}

// ---------------------------------------------------------------------------
// K3 (fallback): standalone softmax. grid 32 x 1024
// ---------------------------------------------------------------------------
__global__ __launch_bounds__(1024) void softmax_kernel(
    const float* __restrict__ score_part, int nplanes,
    const float* __restrict__ vb,
    const int* __restrict__ mask, const float* __restrict__ cov,
    const int* __restrict__ ucov,
    float* __restrict__ attn_out, float* __restrict__ cov_out)
{
    __shared__ float redA[16], redB[16];
    __shared__ float bc0, bc1;
    const int b = blockIdx.x, tid = threadIdx.x;
    const int i0 = b * 2048 + tid, i1 = i0 + 1024;
    const float vbv = vb[0];
    const int uc = *ucov;

    float s0 = 0.f, s1 = 0.f;
    for (int p = 0; p < nplanes; p++) {
        s0 += score_part[(size_t)p * 65536 + i0];
        s1 += score_part[(size_t)p * 65536 + i1];
    }
    s0 = (s0 + vbv) * (float)mask[i0];
    s1 = (s1 + vbv) * (float)mask[i1];

    float m = fmaxf(s0, s1);
#pragma unroll
    for (int off = 1; off < 64; off <<= 1) m = fmaxf(m, __shfl_xor(m, off));
    if ((tid & 63) == 0) redA[tid >> 6] = m;
    __syncthreads();
    if (tid < 16) {
        float v = redA[tid];
#pragma unroll
        for (int off = 1; off < 16; off <<= 1) v = fmaxf(v, __shfl_xor(v, off));
        if (tid == 0) bc0 = v;
    }
    __syncthreads();
    const float M = bc0;

    float e0 = __expf(s0 - M), e1 = __expf(s1 - M);
    float s = e0 + e1;
#pragma unroll
    for (int off = 1; off < 64; off <<= 1) s += __shfl_xor(s, off);
    if ((tid & 63) == 0) redB[tid >> 6] = s;
    __syncthreads();
    if (tid < 16) {
        float v = redB[tid];
#pragma unroll
        for (int off = 1; off < 16; off <<= 1) v += __shfl_xor(v, off);
        if (tid == 0) bc1 = v;
    }
    __syncthreads();
    const float inv = 1.f / bc1;

    float a0 = e0 * inv, a1 = e1 * inv;
    attn_out[i0] = a0;
    attn_out[i1] = a1;
    cov_out[i0] = a0 + (uc ? cov[i0] : 0.f);
    cov_out[i1] = a1 + (uc ? cov[i1] : 0.f);
}

// ---------------------------------------------------------------------------
// Fallback path (ws too small for bf16 enc): fp32-staging gemm + atomics.
// ---------------------------------------------------------------------------
#define BM 128
#define BN 128
#define BK 32
#define LDT 40
__global__ __launch_bounds__(256) void score_gemm_f32(
    const float* __restrict__ enc, const unsigned short* __restrict__ wst,
    const float* __restrict__ base_part, const float* __restrict__ cov,
    const float* __restrict__ wc, const float* __restrict__ vk,
    const float* __restrict__ wsb, const float* __restrict__ whb,
    const float* __restrict__ wcb,
    const int* __restrict__ ucov, float* __restrict__ score)
{
    __shared__ unsigned short As[BM * LDT];
    __shared__ unsigned short Bs[BN * LDT];
    __shared__ float covS[BM];
    __shared__ float baseS[BN], wcS[BN], vvS[BN];
    const int tid = threadIdx.x;
    const int row0 = blockIdx.x * BM, u0 = blockIdx.y * BN;
    const int b = row0 >> 11;
    const int use_cov = *ucov;
    if (tid < BM) covS[tid] = use_cov ? cov[row0 + tid] : 0.f;
    if (tid < BN) {
        int u = u0 + tid;
        float s = wsb[u] + whb[u] + (use_cov ? wcb[u] : 0.f);
#pragma unroll
        for (int p = 0; p < 8; p++) s += base_part[p * 32768 + b * 1024 + u];
        baseS[tid] = s;
        wcS[tid] = use_cov ? wc[u] : 0.f;
        vvS[tid] = vk[u];
    }
    const int lane = tid & 63, wid = tid >> 6;
    const int wm = wid >> 1, wn = wid & 1;
    const int l16 = lane & 15, quad = lane >> 4;
    f32x4 acc[4][4] = {};
    for (int k0 = 0; k0 < 1024; k0 += BK) {
        __syncthreads();
#pragma unroll
        for (int i = 0; i < 4; i++) {
            int f = i * 256 + tid;
            int r = f >> 3, c4 = f & 7;
            const float* p = enc + (size_t)(row0 + r) * 1024 + k0 + c4 * 4;
            ushort4 w;
            w.x = f2bf(p[0]); w.y = f2bf(p[1]); w.z = f2bf(p[2]); w.w = f2bf(p[3]);
            *(ushort4*)&As[r * LDT + c4 * 4] = w;
        }
#pragma unroll
        for (int i = 0; i < 2; i++) {
            int f = i * 256 + tid;
            int r = f >> 2, c8 = f & 3;
            uint4 w = *(const uint4*)(wst + (size_t)(u0 + r) * 1024 + k0 + c8 * 8);
            *(uint4*)&Bs[r * LDT + c8 * 8] = w;
        }
        __syncthreads();
        short8 a[4], bb[4];
#pragma unroll
        for (int t = 0; t < 4; t++) {
            a[t]  = *(const short8*)&As[(wm * 64 + t * 16 + l16) * LDT + quad * 8];
            bb[t] = *(const short8*)&Bs[(wn * 64 + t * 16 + l16) * LDT + quad * 8];
        }
#pragma unroll
        for (int i = 0; i < 4; i++)
#pragma unroll
            for (int j = 0; j < 4; j++)
                acc[i][j] = __builtin_amdgcn_mfma_f32_16x16x32_bf16(a[i], bb[j], acc[i][j], 0, 0, 0);
    }
#pragma unroll
    for (int i = 0; i < 4; i++) {
        float part[4] = {0.f, 0.f, 0.f, 0.f};
#pragma unroll
        for (int r = 0; r < 4; r++) {
            float cv = covS[wm * 64 + i * 16 + quad * 4 + r];
#pragma unroll
            for (int j = 0; j < 4; j++) {
                int ul = wn * 64 + j * 16 + l16;
                part[r] += fast_tanh(acc[i][j][r] + baseS[ul] + cv * wcS[ul]) * vvS[ul];
            }
        }
#pragma unroll
        for (int r = 0; r < 4; r++) {
            float v = part[r];
            v += __shfl_xor(v, 1);
            v += __shfl_xor(v, 2);
            v += __shfl_xor(v, 4);
            v += __shfl_xor(v, 8);
            if (l16 == 0)
                atomicAdd(&score[row0 + wm * 64 + i * 16 + quad * 4 + r], v);
        }
    }
}

__global__ __launch_bounds__(256) void context_f32(const float* __restrict__ enc,
                                                   const float* __restrict__ attn,
                                                   float* __restrict__ ctx) {
    __shared__ float aS[128];
    const int b = blockIdx.x, lc = blockIdx.y, tid = threadIdx.x;
    const int l0 = lc * 128;
    if (tid < 128) aS[tid] = attn[b * 2048 + l0 + tid];
    __syncthreads();
    const float* p = enc + ((size_t)(b * 2048 + l0)) * 1024 + tid * 4;
    f32x4 acc = {0.f, 0.f, 0.f, 0.f};
#pragma unroll 4
    for (int l = 0; l < 128; l++) acc += *(const f32x4*)(p + (size_t)l * 1024) * aS[l];
    float* o = ctx + b * 1024 + tid * 4;
    atomicAdd(o + 0, acc.x);
    atomicAdd(o + 1, acc.y);
    atomicAdd(o + 2, acc.z);
    atomicAdd(o + 3, acc.w);
}

__global__ __launch_bounds__(256) void prep2_kernel(
    const float* __restrict__ ws, unsigned short* __restrict__ wst,
    const float* __restrict__ dh, const float* __restrict__ whk,
    float* __restrict__ base_part)
{
    __shared__ unsigned short tile[64][65];
    __shared__ float dS[128];
    const int bid = blockIdx.x, tid = threadIdx.x;
    if (bid < 256) {
        const int e0 = (bid & 15) * 64, u0 = (bid >> 4) * 64;
#pragma unroll
        for (int i = 0; i < 16; i++) {
            int idx = i * 256 + tid;
            int r = idx >> 6, c = idx & 63;
            tile[r][c] = f2bf(ws[(size_t)(e0 + r) * 1024 + u0 + c]);
        }
        __syncthreads();
#pragma unroll
        for (int i = 0; i < 16; i++) {
            int idx = i * 256 + tid;
            int r = idx >> 6, c = idx & 63;
            wst[(size_t)(u0 + r) * 1024 + e0 + c] = tile[c][r];
        }
    } else {
        const int b3 = bid - 256;
        const int b = b3 & 31, ec = b3 >> 5;
        const int e0 = ec * 128;
        if (tid < 128) dS[tid] = dh[b * 1024 + e0 + tid];
        __syncthreads();
        f32x4 acc = {0.f, 0.f, 0.f, 0.f};
#pragma unroll 4
        for (int e = 0; e < 128; e++)
            acc += dS[e] * *(const f32x4*)(whk + (size_t)(e0 + e) * 1024 + tid * 4);
        *(f32x4*)(base_part + (size_t)ec * 32768 + b * 1024 + tid * 4) = acc;
    }
}

// ---------------------------------------------------------------------------
extern "C" void kernel_launch(void* const* d_in, const int* in_sizes, int n_in,
                              void* d_out, int out_size, void* d_ws, size_t ws_size,
                              hipStream_t stream) {
    const float* dec_hidden = (const float*)d_in[0];
    const float* enc        = (const float*)d_in[1];
    const float* prev_cov   = (const float*)d_in[2];
    const float* Ws_k       = (const float*)d_in[3];
    const float* Ws_b       = (const float*)d_in[4];
    const float* Wh_k       = (const float*)d_in[5];
    const float* Wh_b       = (const float*)d_in[6];
    const float* Wc_k       = (const float*)d_in[7];
    const float* Wc_b       = (const float*)d_in[8];
    const float* V_k        = (const float*)d_in[9];
    const float* V_b        = (const float*)d_in[10];
    const int*   mask       = (const int*)d_in[11];
    const int*   ucov       = (const int*)d_in[12];

    float* out_ctx  = (float*)d_out;
    float* out_attn = out_ctx + 32 * 1024;
    float* out_cov  = out_attn + 65536;

    char* ws = (char*)d_ws;
    unsigned short* wst = (unsigned short*)ws;                    // 2 MB
    float* base_part  = (float*)(ws + 2097152);                   // 1 MB  [8][32768]
    float* score_part = (float*)(ws + 3145728);                   // 2 MB  (4 planes used)
    unsigned short* encB = (unsigned short*)(ws + 5242880);       // 128 MB
    const size_t need_fast = 5242880 + (size_t)32 * 2048 * 1024 * 2;

    if (ws_size >= need_fast) {
        prep_kernel<<<16896, 256, 0, stream>>>(enc, encB, Ws_k, wst, dec_hidden, Wh_k, base_part);
        score_gemm_8ph<<<dim3(1024), dim3(512), 0, stream>>>(
            encB, wst, base_part, prev_cov, Wc_k, V_k, Ws_b, Wh_b, Wc_b, ucov, score_part);
        context_fused<<<dim3(32, 16), 512, 0, stream>>>(
            encB, score_part, 4, V_b, mask, prev_cov, ucov, out_attn, out_cov, out_ctx);
    } else {
        hipMemsetAsync(score_part, 0, 65536 * sizeof(float), stream);
        hipMemsetAsync(out_ctx, 0, 32 * 1024 * sizeof(float), stream);
        prep2_kernel<<<512, 256, 0, stream>>>(Ws_k, wst, dec_hidden, Wh_k, base_part);
        score_gemm_f32<<<dim3(512, 8), 256, 0, stream>>>(
            enc, wst, base_part, prev_cov, Wc_k, V_k, Ws_b, Wh_b, Wc_b, ucov, score_part);
        softmax_kernel<<<32, 1024, 0, stream>>>(score_part, 1, V_b, mask, prev_cov, ucov, out_attn, out_cov);
        context_f32<<<dim3(32, 16), 256, 0, stream>>>(enc, out_attn, out_ctx);
    }
}